// Round 5
// baseline (98.618 us; speedup 1.0000x reference)
//
#include <hip/hip_runtime.h>

// SpatialIndependentDistribution, round 12: LDS-free, barrier-free.
// R11 post-mortem: two-phase staging was neutral -> the stall is the
// staging->barrier->LDS-round-trip structure, not the staging loads.
// Weights (46KB) are L2-resident after warmup; each wave now loads its
// pre-swizzled A-fragments directly from global per step, coalesced
// (wave covers the full 1KB matrix), double-buffered one step ahead
// (raw f32x4 next-buffers; cvt_pkrtz at consumption => vmcnt wait lands
// a full iteration after issue). No __shared__, no __syncthreads, no
// block-wide vmcnt drain. Grid 1024x256 = 4 blocks/CU: whole grid
// co-resident, no dispatch tail. w3/head row-masks dropped (masked rows
// only feed D rows q4+2/q4+3 which the epilogue never reads).
// Keeps R9: 64 px/wave, 4 chains, packed-f16 relu, stage-parallel MFMA
// issue, xs[16] channel prefetch, quad-parallel epilogue.

#define NEG_HALF_LOG_2PI -0.91893853320467274f

typedef _Float16 f16x4 __attribute__((ext_vector_type(4)));
typedef __fp16   hf2   __attribute__((ext_vector_type(2)));
typedef float    f32x4 __attribute__((ext_vector_type(4)));

__device__ inline f16x4 pack_f16(f32x4 v) {
    hf2 p0 = __builtin_amdgcn_cvt_pkrtz(v[0], v[1]);
    hf2 p1 = __builtin_amdgcn_cvt_pkrtz(v[2], v[3]);
    f16x4 r;
    __builtin_memcpy(&r, &p0, 4);
    __builtin_memcpy((char*)&r + 4, &p1, 4);
    return r;
}

// relu after pack: 2 cvt_pkrtz + 2 v_pk_max_f16
__device__ inline f16x4 relu_pack(f32x4 d) {
    hf2 p0 = __builtin_amdgcn_cvt_pkrtz(d[0], d[1]);
    hf2 p1 = __builtin_amdgcn_cvt_pkrtz(d[2], d[3]);
    f16x4 r;
    __builtin_memcpy(&r, &p0, 4);
    __builtin_memcpy((char*)&r + 4, &p1, 4);
    const f16x4 z = {(_Float16)0, (_Float16)0, (_Float16)0, (_Float16)0};
    return __builtin_elementwise_max(r, z);
}

__global__ __launch_bounds__(256, 4) void spatial_main(
    const float* __restrict__ samples,   // [64,16,64,64]
    const float* __restrict__ n1_b1,     // [16]
    const float* __restrict__ n1_w2,     // [16,16]
    const float* __restrict__ n1_b2,     // [16]
    const float* __restrict__ n1_w3,     // [2,16]
    const float* __restrict__ n1_b3,     // [2]
    const float* __restrict__ w1,        // [15,16,16] zero-padded triangular
    const float* __restrict__ b1,        // [15,16]
    const float* __restrict__ w2,        // [15,16,16]
    const float* __restrict__ b2,        // [15,16]
    const float* __restrict__ w3,        // [15,2,16]
    const float* __restrict__ b3,        // [15,2]
    float* __restrict__ out)             // [64,64,64]
{
    const int tid   = threadIdx.x;
    const int lane  = tid & 63;
    const int wv    = tid >> 6;
    const int q     = lane >> 4;          // quad 0..3
    const int col   = lane & 15;
    const int q4    = q << 2;
    const int roff  = col * 16 + q4;      // A-frag: lane reads W[col][q4..q4+3]
    const int w3off = ((col & 1) << 4) + q4;  // w3 A-frag (rows mod-4 replicated)

    // ---- step-0 fragment loads issued first (latency hides under bx/xs/head)
    f32x4 ra1 = *(const f32x4*)(w1 + roff);
    f32x4 ra2 = *(const f32x4*)(w2 + roff);
    f32x4 ra3 = *(const f32x4*)(w3 + w3off);
    f32x4 c1c = *(const f32x4*)(b1 + q4);
    f32x4 c2c = *(const f32x4*)(b2 + q4);

    // ---- pixel loads ----
    const int pbase = blockIdx.x * 256 + wv * 64;       // wave's first pixel
    const int b     = pbase >> 12;
    const int hw    = pbase & 4095;
    const float* xw = samples + ((size_t)b << 16) + hw; // + ch*4096 + 0..63

    f16x4 bx[4];
    #pragma unroll
    for (int ch = 0; ch < 4; ++ch)
        #pragma unroll
        for (int i = 0; i < 4; ++i)
            bx[ch][i] = (_Float16)xw[((q4 + i) << 12) + (ch << 4) + col];

    // all 16 per-pixel channel values: coalesced 256B/wave loads
    float xs[16];
    #pragma unroll
    for (int c = 0; c < 16; ++c)
        xs[c] = xw[(c << 12) + lane];

    float accz, accl;
    {   // head: n1 net on zero input; B operand pixel-independent; 2 MFMAs
        f32x4 c1h = *(const f32x4*)(n1_b1 + q4);        // C-layout == B-layout
        f16x4 h1h = relu_pack(c1h);
        f16x4 a2h = pack_f16(*(const f32x4*)(n1_w2 + roff));
        f32x4 c2h = *(const f32x4*)(n1_b2 + q4);
        f32x4 d2h = __builtin_amdgcn_mfma_f32_16x16x16f16(a2h, h1h, c2h, 0, 0, 0);
        f16x4 h2h = relu_pack(d2h);
        f16x4 a3h = pack_f16(*(const f32x4*)(n1_w3 + w3off));  // mask dropped
        f32x4 c3h = {n1_b3[0], n1_b3[1], 0.0f, 0.0f};
        f32x4 d3h = __builtin_amdgcn_mfma_f32_16x16x16f16(a3h, h2h, c3h, 0, 0, 0);
        float ls = d3h[1];
        float z0 = (xs[0] - d3h[0]) * __expf(-ls);
        accz = z0 * z0;
        accl = ls;
    }

    // ---- 15 autoregressive steps; frags direct-from-global (L2-resident),
    // double-buffered one full step ahead ----
    #pragma unroll
    for (int s = 0; s < 15; ++s) {
        // convert this step's frags (loaded one iteration ago -> data arrived)
        f16x4 a1 = pack_f16(ra1);
        f16x4 a2 = pack_f16(ra2);
        f16x4 a3 = pack_f16(ra3);
        f32x4 c1 = c1c;
        f32x4 c2 = c2c;

        // issue next step's loads (dead at s==14, compile-time)
        if (s < 14) {
            ra1 = *(const f32x4*)(w1 + (s + 1) * 256 + roff);
            ra2 = *(const f32x4*)(w2 + (s + 1) * 256 + roff);
            ra3 = *(const f32x4*)(w3 + (s + 1) * 32 + w3off);
            c1c = *(const f32x4*)(b1 + (s + 1) * 16 + q4);
            c2c = *(const f32x4*)(b2 + (s + 1) * 16 + q4);
        }
        f32x4 c3 = {b3[s * 2 + 0], b3[s * 2 + 1], 0.0f, 0.0f};     // s_load

        // layer 1: 4 independent MFMAs issued back-to-back
        f32x4 d1[4];
        #pragma unroll
        for (int ch = 0; ch < 4; ++ch)
            d1[ch] = __builtin_amdgcn_mfma_f32_16x16x16f16(a1, bx[ch], c1, 0, 0, 0);
        f16x4 h1[4];
        #pragma unroll
        for (int ch = 0; ch < 4; ++ch)
            h1[ch] = relu_pack(d1[ch]);
        // layer 2
        f32x4 d2[4];
        #pragma unroll
        for (int ch = 0; ch < 4; ++ch)
            d2[ch] = __builtin_amdgcn_mfma_f32_16x16x16f16(a2, h1[ch], c2, 0, 0, 0);
        f16x4 h2[4];
        #pragma unroll
        for (int ch = 0; ch < 4; ++ch)
            h2[ch] = relu_pack(d2[ch]);
        // layer 3
        f32x4 d3[4];
        #pragma unroll
        for (int ch = 0; ch < 4; ++ch)
            d3[ch] = __builtin_amdgcn_mfma_f32_16x16x16f16(a3, h2[ch], c3, 0, 0, 0);

        // quad q takes chain q's epilogue (constant indices per select arm)
        float loc = q == 0 ? d3[0][0] : q == 1 ? d3[1][0] : q == 2 ? d3[2][0] : d3[3][0];
        float ls  = q == 0 ? d3[0][1] : q == 1 ? d3[1][1] : q == 2 ? d3[2][1] : d3[3][1];
        float z   = (xs[s + 1] - loc) * __expf(-ls);
        accz = fmaf(z, z, accz);
        accl += ls;
    }

    // out = -0.5*accz - accl + 16*(-0.5*log(2pi)); all 64 lanes write coalesced
    out[pbase + lane] = fmaf(-0.5f, accz, 16.0f * NEG_HALF_LOG_2PI - accl);
}

extern "C" void kernel_launch(void* const* d_in, const int* in_sizes, int n_in,
                              void* d_out, int out_size, void* d_ws, size_t ws_size,
                              hipStream_t stream) {
    const float* samples = (const float*)d_in[0];
    // d_in[1] = n1_w1 unused (first-channel input is zeros)
    const float* n1_b1   = (const float*)d_in[2];
    const float* n1_w2   = (const float*)d_in[3];
    const float* n1_b2   = (const float*)d_in[4];
    const float* n1_w3   = (const float*)d_in[5];
    const float* n1_b3   = (const float*)d_in[6];
    const float* w1      = (const float*)d_in[7];
    const float* b1      = (const float*)d_in[8];
    const float* w2      = (const float*)d_in[9];
    const float* b2      = (const float*)d_in[10];
    const float* w3      = (const float*)d_in[11];
    const float* b3      = (const float*)d_in[12];
    float* out = (float*)d_out;

    // 262144 pixels / 64 per wave / 4 waves per block = 1024 blocks
    // = 4 blocks/CU: whole grid co-resident, no barrier, no tail
    spatial_main<<<dim3(1024), dim3(256), 0, stream>>>(
        samples, n1_b1, n1_w2, n1_b2, n1_w3, n1_b3,
        w1, b1, w2, b2, w3, b3, out);
}

// Round 6
// 94.461 us; speedup vs baseline: 1.0440x; 1.0440x over previous
//
#include <hip/hip_runtime.h>

// SpatialIndependentDistribution, round 13: consolidation — resubmit of the
// best-measured kernel (R11, 96.2 µs) after R12's LDS-free probe regressed
// slightly (98.6). Three structural variants (R9/R11/R12) land within
// ±2.5 µs: the timed metric is dominated by ~86-88 µs of harness fill
// dispatches (75-80% HBM peak) + launch gaps; the kernel slice itself is
// ~4-6 µs, at its issue-count floor. This round confirms reproducibility
// of the best artifact before declaring the practical ceiling.
// Structure: LDS-staged pre-swizzled f16 A-frags (two-phase staging: all
// global loads issued, then pack+ds_write), 512-thr blocks (512 blocks),
// 64 px/wave, 4 MFMA chains stage-parallel, frag double-buffer one step
// ahead, packed-f16 relu, xs[16] channel prefetch, quad-parallel epilogue.

#define NEG_HALF_LOG_2PI -0.91893853320467274f

typedef _Float16 f16x4 __attribute__((ext_vector_type(4)));
typedef __fp16   hf2   __attribute__((ext_vector_type(2)));
typedef float    f32x4 __attribute__((ext_vector_type(4)));

__device__ inline f16x4 pack_f16(f32x4 v) {
    hf2 p0 = __builtin_amdgcn_cvt_pkrtz(v[0], v[1]);
    hf2 p1 = __builtin_amdgcn_cvt_pkrtz(v[2], v[3]);
    f16x4 r;
    __builtin_memcpy(&r, &p0, 4);
    __builtin_memcpy((char*)&r + 4, &p1, 4);
    return r;
}

// relu after pack: 2 cvt_pkrtz + 2 v_pk_max_f16
__device__ inline f16x4 relu_pack(f32x4 d) {
    hf2 p0 = __builtin_amdgcn_cvt_pkrtz(d[0], d[1]);
    hf2 p1 = __builtin_amdgcn_cvt_pkrtz(d[2], d[3]);
    f16x4 r;
    __builtin_memcpy(&r, &p0, 4);
    __builtin_memcpy((char*)&r + 4, &p1, 4);
    const f16x4 z = {(_Float16)0, (_Float16)0, (_Float16)0, (_Float16)0};
    return __builtin_elementwise_max(r, z);
}

__global__ __launch_bounds__(512, 4) void spatial_main(
    const float* __restrict__ samples,   // [64,16,64,64]
    const float* __restrict__ n1_b1,     // [16]
    const float* __restrict__ n1_w2,     // [16,16]
    const float* __restrict__ n1_b2,     // [16]
    const float* __restrict__ n1_w3,     // [2,16]
    const float* __restrict__ n1_b3,     // [2]
    const float* __restrict__ w1,        // [15,16,16] zero-padded triangular
    const float* __restrict__ b1,        // [15,16]
    const float* __restrict__ w2,        // [15,16,16]
    const float* __restrict__ b2,        // [15,16]
    const float* __restrict__ w3,        // [15,2,16]
    const float* __restrict__ b3,        // [15,2]
    float* __restrict__ out)             // [64,64,64]
{
    // A-fragments: fA[sl*256 + lane*4 + i] = W_sl[lane&15][4*(lane>>4)+i], f16
    __shared__ _Float16 fA[45 * 256];    // 23040 B
    __shared__ float    fC[15 * 2 * 16]; // 1920 B  (b1,b2 as MFMA C operands)

    const int tid   = threadIdx.x;       // 0..511
    const int lane  = tid & 63;
    const int wv    = tid >> 6;          // 0..7
    const int q     = lane >> 4;         // quad 0..3
    const int col   = lane & 15;
    const int lane4 = lane << 2;
    const int q4    = q << 2;
    const int roff  = col * 16 + q4;     // head A-frag: [row][4q], contiguous

    // ---- pixel loads first: scattered bx + coalesced xs, in flight early ----
    const int pbase = blockIdx.x * 512 + wv * 64;       // wave's first pixel
    const int b     = pbase >> 12;
    const int hw    = pbase & 4095;
    const float* xw = samples + ((size_t)b << 16) + hw; // + ch*4096 + 0..63

    f16x4 bx[4];
    #pragma unroll
    for (int ch = 0; ch < 4; ++ch)
        #pragma unroll
        for (int i = 0; i < 4; ++i)
            bx[ch][i] = (_Float16)xw[((q4 + i) << 12) + (ch << 4) + col];

    float xs[16];
    #pragma unroll
    for (int c = 0; c < 16; ++c)
        xs[c] = xw[(c << 12) + lane];

    // ---- staging phase A: issue ALL weight loads (masked, independent) ----
    // w1/w2 fragments: 1920 items over 512 threads -> 4 masked rounds
    f32x4 t1[4];
    #pragma unroll
    for (int i = 0; i < 4; ++i) {
        int j = tid + i * 512;
        if (j < 1920) {
            int m   = j >> 6;
            int rem = j & 63;
            int r   = rem >> 2;
            int c   = rem & 3;
            const float* src = (m < 15) ? (w1 + m * 256) : (w2 + (m - 15) * 256);
            t1[i] = *(const f32x4*)(src + r * 16 + (c << 2));
        }
    }
    // w3 fragments: 960 items -> 2 masked rounds
    f32x4 t2[2];
    #pragma unroll
    for (int i = 0; i < 2; ++i) {
        int j = tid + i * 512;
        t2[i] = f32x4{0.f, 0.f, 0.f, 0.f};
        if (j < 960) {
            int s  = j >> 6;
            int ln = j & 63;
            int r  = ln & 15;
            int qq = ln >> 4;
            if ((r & 3) < 2)
                t2[i] = *(const f32x4*)(w3 + s * 32 + ((r & 1) << 4) + (qq << 2));
        }
    }
    // biases: 480 items -> 1 masked round
    float t3 = 0.f;
    if (tid < 480) {
        int s = tid >> 5, layer = (tid >> 4) & 1, o = tid & 15;
        t3 = layer ? b2[s * 16 + o] : b1[s * 16 + o];
    }

    // ---- staging phase B: pack + LDS writes ----
    #pragma unroll
    for (int i = 0; i < 4; ++i) {
        int j = tid + i * 512;
        if (j < 1920) {
            int m   = j >> 6;
            int rem = j & 63;
            int r   = rem >> 2;
            int c   = rem & 3;
            int sl  = (m < 15) ? (m * 3) : ((m - 15) * 3 + 1);
            *(f16x4*)&fA[sl * 256 + (((c << 4) + r) << 2)] = pack_f16(t1[i]);
        }
    }
    #pragma unroll
    for (int i = 0; i < 2; ++i) {
        int j = tid + i * 512;
        if (j < 960) {
            int s  = j >> 6;
            int ln = j & 63;
            *(f16x4*)&fA[(s * 3 + 2) * 256 + (ln << 2)] = pack_f16(t2[i]);
        }
    }
    if (tid < 480) fC[tid] = t3;

    // ---- head: n1 net on zero input; B operand pixel-independent; 2 MFMAs ----
    float accz, accl;
    {
        f32x4 c1h = *(const f32x4*)(n1_b1 + q4);        // C-layout == B-layout
        f16x4 h1h = relu_pack(c1h);
        f16x4 a2h = pack_f16(*(const f32x4*)(n1_w2 + roff));
        f32x4 c2h = *(const f32x4*)(n1_b2 + q4);
        f32x4 d2h = __builtin_amdgcn_mfma_f32_16x16x16f16(a2h, h1h, c2h, 0, 0, 0);
        f16x4 h2h = relu_pack(d2h);
        f32x4 v3h = {0.f, 0.f, 0.f, 0.f};
        if ((col & 3) < 2) v3h = *(const f32x4*)(n1_w3 + ((col & 1) << 4) + q4);
        f16x4 a3h = pack_f16(v3h);
        f32x4 c3h = {n1_b3[0], n1_b3[1], 0.0f, 0.0f};
        f32x4 d3h = __builtin_amdgcn_mfma_f32_16x16x16f16(a3h, h2h, c3h, 0, 0, 0);
        float ls = d3h[1];
        float z0 = (xs[0] - d3h[0]) * __expf(-ls);
        accz = z0 * z0;
        accl = ls;
    }

    __syncthreads();

    // ---- 15 autoregressive steps, frags from LDS, explicit double-buffer:
    // step s+1's 5 ds_reads issue before step s's MFMA chain ----
    f16x4 a1c = *(const f16x4*)&fA[0 * 256 + lane4];
    f16x4 a2c = *(const f16x4*)&fA[1 * 256 + lane4];
    f16x4 a3c = *(const f16x4*)&fA[2 * 256 + lane4];
    f32x4 c1c = *(const f32x4*)&fC[0 * 16 + q4];
    f32x4 c2c = *(const f32x4*)&fC[1 * 16 + q4];

    #pragma unroll
    for (int s = 0; s < 15; ++s) {
        // prefetch next step's fragments (dead code at s==14, compile-time)
        f16x4 a1n, a2n, a3n;
        f32x4 c1n, c2n;
        if (s < 14) {
            a1n = *(const f16x4*)&fA[((s + 1) * 3 + 0) * 256 + lane4];
            a2n = *(const f16x4*)&fA[((s + 1) * 3 + 1) * 256 + lane4];
            a3n = *(const f16x4*)&fA[((s + 1) * 3 + 2) * 256 + lane4];
            c1n = *(const f32x4*)&fC[((s + 1) * 2 + 0) * 16 + q4];
            c2n = *(const f32x4*)&fC[((s + 1) * 2 + 1) * 16 + q4];
        }
        f32x4 c3 = {b3[s * 2 + 0], b3[s * 2 + 1], 0.0f, 0.0f};     // s_load

        // layer 1: 4 independent MFMAs issued back-to-back
        f32x4 d1[4];
        #pragma unroll
        for (int ch = 0; ch < 4; ++ch)
            d1[ch] = __builtin_amdgcn_mfma_f32_16x16x16f16(a1c, bx[ch], c1c, 0, 0, 0);
        f16x4 h1[4];
        #pragma unroll
        for (int ch = 0; ch < 4; ++ch)
            h1[ch] = relu_pack(d1[ch]);
        // layer 2
        f32x4 d2[4];
        #pragma unroll
        for (int ch = 0; ch < 4; ++ch)
            d2[ch] = __builtin_amdgcn_mfma_f32_16x16x16f16(a2c, h1[ch], c2c, 0, 0, 0);
        f16x4 h2[4];
        #pragma unroll
        for (int ch = 0; ch < 4; ++ch)
            h2[ch] = relu_pack(d2[ch]);
        // layer 3
        f32x4 d3[4];
        #pragma unroll
        for (int ch = 0; ch < 4; ++ch)
            d3[ch] = __builtin_amdgcn_mfma_f32_16x16x16f16(a3c, h2[ch], c3, 0, 0, 0);

        // quad q takes chain q's epilogue (constant indices per select arm)
        float loc = q == 0 ? d3[0][0] : q == 1 ? d3[1][0] : q == 2 ? d3[2][0] : d3[3][0];
        float ls  = q == 0 ? d3[0][1] : q == 1 ? d3[1][1] : q == 2 ? d3[2][1] : d3[3][1];
        float z   = (xs[s + 1] - loc) * __expf(-ls);
        accz = fmaf(z, z, accz);
        accl += ls;

        // rotate double-buffer
        a1c = a1n; a2c = a2n; a3c = a3n; c1c = c1n; c2c = c2n;
    }

    // out = -0.5*accz - accl + 16*(-0.5*log(2pi)); all 64 lanes write coalesced
    out[pbase + lane] = fmaf(-0.5f, accz, 16.0f * NEG_HALF_LOG_2PI - accl);
}

extern "C" void kernel_launch(void* const* d_in, const int* in_sizes, int n_in,
                              void* d_out, int out_size, void* d_ws, size_t ws_size,
                              hipStream_t stream) {
    const float* samples = (const float*)d_in[0];
    // d_in[1] = n1_w1 unused (first-channel input is zeros)
    const float* n1_b1   = (const float*)d_in[2];
    const float* n1_w2   = (const float*)d_in[3];
    const float* n1_b2   = (const float*)d_in[4];
    const float* n1_w3   = (const float*)d_in[5];
    const float* n1_b3   = (const float*)d_in[6];
    const float* w1      = (const float*)d_in[7];
    const float* b1      = (const float*)d_in[8];
    const float* w2      = (const float*)d_in[9];
    const float* b2      = (const float*)d_in[10];
    const float* w3      = (const float*)d_in[11];
    const float* b3      = (const float*)d_in[12];
    float* out = (float*)d_out;

    // 262144 pixels / 64 per wave / 8 waves per block = 512 blocks
    spatial_main<<<dim3(512), dim3(512), 0, stream>>>(
        samples, n1_b1, n1_w2, n1_b2, n1_w3, n1_b3,
        w1, b1, w2, b2, w3, b3, out);
}